// Round 11
// baseline (96.026 us; speedup 1.0000x reference)
//
#include <hip/hip_runtime.h>
#include <hip/hip_bf16.h>
#include <math.h>

#define BB 64
#define HH 80
#define WW 3000
#define RAD 16
#define TW 96             // output columns per strip
#define XSW 68            // Xs words/row: 64 data + 4 pad (68 % 32 == 4 -> b128 bank-spread)
#define HXS 116           // Hxp col stride: 112 raw rows + 4 pad (116 % 32 == 20 -> b128 bank-spread)
#define S_PER_BLK 4       // strips per block (pipelined via L2 prefetch)
#define NKGRP 8           // 32 strips / S_PER_BLK
#define NT 1024
#define EPSF 1e-8f

#define XS_WORDS (HH * XSW)             // 5440
#define HXP_OFF  XS_WORDS
#define HXP_WORDS (TW * HXS)            // 11136
#define ICH_OFF  (XS_WORDS + HXP_WORDS) // 16576
#define TOT_WORDS (ICH_OFF + HH)        // 16656 words = 66624 B -> 2 blocks/CU (32/32 wave slots)

typedef float f32x2 __attribute__((ext_vector_type(2)));

__device__ __forceinline__ float bflo(uint32_t w) { return __uint_as_float(w << 16); }
__device__ __forceinline__ float bfhi(uint32_t w) { return __uint_as_float(w & 0xffff0000u); }
__device__ __forceinline__ uint32_t packbf2(float lo, float hi) {
    union { __hip_bfloat162 h2; uint32_t u; } u;
    u.h2 = __hip_bfloat162(__float2bfloat16(lo), __float2bfloat16(hi));
    return u.u;
}
// unpack a bf16-packed word into f32x2 {lo, hi}; pk_add accumulates both halves
__device__ __forceinline__ f32x2 uw(uint32_t w) {
    f32x2 r; r.x = bflo(w); r.y = bfhi(w); return r;
}

// barrier that orders LDS (lgkmcnt) but does NOT drain vmcnt — touch loads stay in flight
__device__ __forceinline__ void softbar() {
    __builtin_amdgcn_sched_barrier(0);
    asm volatile("s_waitcnt lgkmcnt(0)" ::: "memory");
    __builtin_amdgcn_s_barrier();
    __builtin_amdgcn_sched_barrier(0);
}

// compile-time-folding element selectors (named registers only — no arrays/unions)
#define E4(V, J) ((J) == 0 ? (V).x : ((J) == 1 ? (V).y : ((J) == 2 ? (V).z : (V).w)))
#define W20(Q) E4((Q) < 4 ? v0 : (Q) < 8 ? v1 : (Q) < 12 ? v2 : (Q) < 16 ? v3 : v4, (Q) & 3)
#define W48(Q) E4((Q) < 4 ? R0 : (Q) < 8 ? R1 : (Q) < 12 ? R2 : (Q) < 16 ? R3 : (Q) < 20 ? R4 : \
                  (Q) < 24 ? R5 : (Q) < 28 ? R6 : (Q) < 32 ? R7 : (Q) < 36 ? R8 : \
                  (Q) < 40 ? R9 : (Q) < 44 ? R10 : R11, (Q) & 3)

__global__ __launch_bounds__(NT, 8)
void localnorm_kernel(const float* __restrict__ in, float* __restrict__ out) {
    extern __shared__ uint32_t smem[];
    uint32_t* Hxp = smem + HXP_OFF;          // Hxp[col][raw_r] at col*HXS + raw_r; raw_r = logical+16
    float* inv_ch = (float*)(smem + ICH_OFF);

    const int t      = threadIdx.x;
    const int kgrp   = blockIdx.x & (NKGRP - 1);
    const int b      = blockIdx.x / NKGRP;
    const int strip0 = kgrp * S_PER_BLK;
    const float* inb = in + (size_t)b * (HH * WW);

    // phase 0 (once): per-row reciprocals + zero Hxp pad rows (raw 0..15 and 96..111).
    // Pads are disjoint from P2's writes (raw 16..95) and persist across strips.
    if (t < HH) {
        int lo = max(t - RAD, 0), hi = min(t + RAD, HH - 1);
        inv_ch[t] = 1.0f / (float)(hi - lo + 1);
    }
    if (t < 768) {
        const int col = t >> 3;
        const int c8  = t & 7;
        const int off = col * HXS + ((c8 < 4) ? (c8 * 4) : (96 + (c8 - 4) * 4));
        *(uint4*)(Hxp + off) = make_uint4(0u, 0u, 0u, 0u);
    }

    #pragma unroll 1
    for (int s = 0; s < S_PER_BLK; ++s) {
        const int c0 = (strip0 + s) * TW;

        // ---- P1: load 128 cols x 80 rows, pack to bf16 pairs -> Xs. 2560 quad-tasks.
        {
            #pragma unroll
            for (int it = 0; it < 3; ++it) {
                const int id = t + it * NT;
                if (it < 2 || id < 2560) {
                    const int row = id >> 5;
                    const int q   = id & 31;
                    const int gc  = c0 - 16 + 4 * q;
                    uint2 w2;
                    if (gc >= 0 && gc + 4 <= WW) {
                        float4 v = *(const float4*)(inb + (size_t)row * WW + gc);
                        w2.x = packbf2(v.x, v.y);
                        w2.y = packbf2(v.z, v.w);
                    } else {
                        float p0 = (gc     >= 0 && gc     < WW) ? inb[(size_t)row * WW + gc]     : 0.f;
                        float p1 = (gc + 1 >= 0 && gc + 1 < WW) ? inb[(size_t)row * WW + gc + 1] : 0.f;
                        float p2 = (gc + 2 >= 0 && gc + 2 < WW) ? inb[(size_t)row * WW + gc + 2] : 0.f;
                        float p3 = (gc + 3 >= 0 && gc + 3 < WW) ? inb[(size_t)row * WW + gc + 3] : 0.f;
                        w2.x = packbf2(p0, p1);
                        w2.y = packbf2(p2, p3);
                    }
                    *(uint2*)(smem + row * XSW + 2 * q) = w2;
                }
            }
        }
        softbar();

        // ---- touch-prefetch next strip into L2/L1: one 4B load per 128B line, dead dest.
        // 80 rows x 5 touches = 400; results never read -> no waitcnt; loads survive softbars.
        if (s + 1 < S_PER_BLK && t < 400) {
            const int row = t / 5;
            const int j   = t - row * 5;
            const int cg  = (strip0 + s + 1) * TW - 16 + ((j < 4) ? j * 32 : 127);
            const int col = min(cg, WW - 1);
            const float* ap = inb + (size_t)row * WW + col;
            float dummy;
            asm volatile("global_load_dword %0, %1, off"
                         : "=v"(dummy) : "v"((uint64_t)(uintptr_t)ap) : "memory");
        }

        // ---- P2: fused horizontal 33-tap sums of x AND x^2; bf16-packed (Sx,Sxx) per col.
        // 80 rows x 12 segs of 8 cols = 960 threads; 5 b128 reads each.
        {
            const int row = t % HH;
            const int seg = t / HH;
            if (seg < 12) {
                const uint32_t* xr = smem + row * XSW + seg * 4;
                uint4 v0 = *(const uint4*)(xr);
                uint4 v1 = *(const uint4*)(xr + 4);
                uint4 v2 = *(const uint4*)(xr + 8);
                uint4 v3 = *(const uint4*)(xr + 12);
                uint4 v4 = *(const uint4*)(xr + 16);
                float l16 = bflo(W20(16));
                f32x2 pA; pA.x = l16;       pA.y = 0.f;
                f32x2 qA; qA.x = l16 * l16; qA.y = 0.f;
                f32x2 pB; pB.x = 0.f; pB.y = 0.f;
                f32x2 qB; qB.x = 0.f; qB.y = 0.f;
                #pragma unroll
                for (int q = 0; q < 16; q += 2) {
                    f32x2 uA = uw(W20(q));
                    f32x2 uB = uw(W20(q + 1));
                    pA += uA;      pB += uB;
                    qA += uA * uA; qB += uB * uB;
                }
                f32x2 ps = pA + pB, qs = qA + qB;
                float ax  = ps.x + ps.y;
                float axx = qs.x + qs.y;
                uint32_t* hw = Hxp + (seg * 8) * HXS + row + 16;
                #pragma unroll
                for (int k = 0; k < 4; ++k) {
                    uint32_t wS = W20(k), wE = W20(k + 16);
                    float lS = bflo(wS), hE = bfhi(wE);
                    float a1x  = ax - lS + hE;
                    float a1xx = axx - lS * lS + hE * hE;
                    hw[(2 * k) * HXS]     = packbf2(ax, axx);
                    hw[(2 * k + 1) * HXS] = packbf2(a1x, a1xx);
                    if (k != 3) {
                        float hS = bfhi(wS), lN = bflo(W20(k + 17));
                        ax  = a1x - hS + lN;
                        axx = a1xx - hS * hS + lN * lN;
                    }
                }
            }
        }
        softbar();

        // ---- P3: vertical 33-tap sums of (Sx,Sxx) via pk_add, bands of 16 rows.
        // 96 cols x 5 bands = 480 threads; 12 contiguous b128 reads (words r0..r0+47).
        {
            const int c    = t % TW;
            const int band = t / TW;
            const int gc   = c0 + c;
            if (band < 5 && gc < WW) {
                const int r0 = band * 16;
                const uint32_t* hp = Hxp + c * HXS + r0;   // raw rows r0 .. r0+47
                uint4 R0  = *(const uint4*)(hp);
                uint4 R1  = *(const uint4*)(hp + 4);
                uint4 R2  = *(const uint4*)(hp + 8);
                uint4 R3  = *(const uint4*)(hp + 12);
                uint4 R4  = *(const uint4*)(hp + 16);
                uint4 R5  = *(const uint4*)(hp + 20);
                uint4 R6  = *(const uint4*)(hp + 24);
                uint4 R7  = *(const uint4*)(hp + 28);
                uint4 R8  = *(const uint4*)(hp + 32);
                uint4 R9  = *(const uint4*)(hp + 36);
                uint4 R10 = *(const uint4*)(hp + 40);
                uint4 R11 = *(const uint4*)(hp + 44);
                f32x2 aA = uw(W48(32));
                f32x2 aB; aB.x = 0.f; aB.y = 0.f;
                #pragma unroll
                for (int q = 0; q < 32; q += 2) {
                    aA += uw(W48(q));
                    aB += uw(W48(q + 1));
                }
                f32x2 acc = aA + aB;                       // {Sx_v, Sxx_v}
                const float icw = 1.0f / (float)(min(gc + RAD, WW - 1) - max(gc - RAD, 0) + 1);
                const int  xwoff  = (c + 16) >> 1;
                const bool hiHf   = ((c + 16) & 1) != 0;
                float* outb = out + (size_t)b * (HH * WW);
                #pragma unroll
                for (int k = 0; k < 16; ++k) {
                    const int r = r0 + k;
                    const float ninv = inv_ch[r] * icw;
                    f32x2 me = acc * ninv;                 // {mean, E[x^2]} via v_pk_mul
                    float var = fmaxf(me.y - me.x * me.x, 1e-24f);
#if defined(__has_builtin) && __has_builtin(__builtin_amdgcn_rsqf)
                    float isd = __builtin_amdgcn_rsqf(var);
#else
                    float isd = __builtin_amdgcn_rcpf(__builtin_amdgcn_sqrtf(var) + EPSF);
#endif
                    uint32_t xw = smem[r * XSW + xwoff];
                    float xv = hiHf ? bfhi(xw) : bflo(xw);
                    outb[(size_t)r * WW + gc] = (xv - me.x) * isd;
                    if (k != 15) {
                        acc += uw(W48(k + 33)) - uw(W48(k));   // 2x v_pk_add_f32
                    }
                }
            }
        }
        if (s + 1 < S_PER_BLK) softbar();   // protect Xs (P3 reads) / Hxp before reuse
    }
}

extern "C" void kernel_launch(void* const* d_in, const int* in_sizes, int n_in,
                              void* d_out, int out_size, void* d_ws, size_t ws_size,
                              hipStream_t stream) {
    const float* in = (const float*)d_in[0];
    float* out = (float*)d_out;

    const size_t lds_bytes = (size_t)TOT_WORDS * sizeof(uint32_t);  // 66624
    static bool attr_set = false;
    if (!attr_set) {
        (void)hipFuncSetAttribute((const void*)localnorm_kernel,
                                  hipFuncAttributeMaxDynamicSharedMemorySize,
                                  (int)lds_bytes);
        attr_set = true;
    }

    dim3 grid(BB * NKGRP);   // 512 blocks = exactly the resident set (2 per CU)
    dim3 block(NT);
    localnorm_kernel<<<grid, block, lds_bytes, stream>>>(in, out);
}

// Round 12
// 38.438 us; speedup vs baseline: 2.4982x; 2.4982x over previous
//
#include <hip/hip_runtime.h>
#include <hip/hip_bf16.h>
#include <math.h>

#define BB 64
#define HH 80
#define WW 3000
#define RAD 16
#define TW 96             // output columns per strip
#define XSW 68            // Xs words/row: 64 data + 4 pad (68 % 32 == 4 -> b128 bank-spread)
#define HXS 116           // Hxp col stride: 112 raw rows + 4 pad (116 % 32 == 20 -> b128 bank-spread)
#define NSTRIP 32         // ceil(3000/96)
#define NT 1024
#define EPSF 1e-8f

#define XS_WORDS (HH * XSW)             // 5440
#define HXP_OFF  XS_WORDS
#define HXP_WORDS (TW * HXS)            // 11136
#define ICH_OFF  (XS_WORDS + HXP_WORDS) // 16576
#define TOT_WORDS (ICH_OFF + HH)        // 16656 words = 66624 B -> 2 blocks/CU (32/32 wave slots)

typedef float f32x2 __attribute__((ext_vector_type(2)));
typedef float f32x4 __attribute__((ext_vector_type(4)));

__device__ __forceinline__ float bflo(uint32_t w) { return __uint_as_float(w << 16); }
__device__ __forceinline__ float bfhi(uint32_t w) { return __uint_as_float(w & 0xffff0000u); }
__device__ __forceinline__ uint32_t packbf2(float lo, float hi) {
    union { __hip_bfloat162 h2; uint32_t u; } u;
    u.h2 = __hip_bfloat162(__float2bfloat16(lo), __float2bfloat16(hi));
    return u.u;
}
// unpack a bf16-packed word into f32x2 {lo, hi}; pk_add accumulates both halves
__device__ __forceinline__ f32x2 uw(uint32_t w) {
    f32x2 r; r.x = bflo(w); r.y = bfhi(w); return r;
}

// compile-time-folding element selectors (named registers only — no arrays/unions)
#define E4(V, J) ((J) == 0 ? (V).x : ((J) == 1 ? (V).y : ((J) == 2 ? (V).z : (V).w)))
#define W20(Q) E4((Q) < 4 ? v0 : (Q) < 8 ? v1 : (Q) < 12 ? v2 : (Q) < 16 ? v3 : v4, (Q) & 3)
#define W48(Q) E4((Q) < 4 ? R0 : (Q) < 8 ? R1 : (Q) < 12 ? R2 : (Q) < 16 ? R3 : (Q) < 20 ? R4 : \
                  (Q) < 24 ? R5 : (Q) < 28 ? R6 : (Q) < 32 ? R7 : (Q) < 36 ? R8 : \
                  (Q) < 40 ? R9 : (Q) < 44 ? R10 : R11, (Q) & 3)

__global__ __launch_bounds__(NT, 8)
void localnorm_kernel(const float* __restrict__ in, float* __restrict__ out) {
    extern __shared__ uint32_t smem[];
    uint32_t* Hxp = smem + HXP_OFF;          // Hxp[col][raw_r] at col*HXS + raw_r; raw_r = logical+16
    float* inv_ch = (float*)(smem + ICH_OFF);

    const int t     = threadIdx.x;
    const int strip = blockIdx.x % NSTRIP;
    const int b     = blockIdx.x / NSTRIP;
    const int c0    = strip * TW;

    // phase 0: per-row reciprocals + zero Hxp pad rows (raw 0..15 and 96..111) for all 96 cols
    if (t < HH) {
        int lo = max(t - RAD, 0), hi = min(t + RAD, HH - 1);
        inv_ch[t] = 1.0f / (float)(hi - lo + 1);
    }
    if (t < 768) {
        const int col = t >> 3;
        const int c8  = t & 7;
        const int off = col * HXS + ((c8 < 4) ? (c8 * 4) : (96 + (c8 - 4) * 4));
        *(uint4*)(Hxp + off) = make_uint4(0u, 0u, 0u, 0u);
    }

    // phase 1: load 128 cols x 80 rows, pack to bf16 pairs. 80 rows x 32 quads = 2560 tasks.
    {
        const float* inb = in + (size_t)b * (HH * WW);
        #pragma unroll
        for (int it = 0; it < 3; ++it) {
            const int id = t + it * NT;
            if (it < 2 || id < 2560) {
                const int row = id >> 5;
                const int q   = id & 31;
                const int gc  = c0 - 16 + 4 * q;
                uint2 w2;
                if (gc >= 0 && gc + 4 <= WW) {
                    float4 v = *(const float4*)(inb + (size_t)row * WW + gc);
                    w2.x = packbf2(v.x, v.y);
                    w2.y = packbf2(v.z, v.w);
                } else {
                    float p0 = (gc     >= 0 && gc     < WW) ? inb[(size_t)row * WW + gc]     : 0.f;
                    float p1 = (gc + 1 >= 0 && gc + 1 < WW) ? inb[(size_t)row * WW + gc + 1] : 0.f;
                    float p2 = (gc + 2 >= 0 && gc + 2 < WW) ? inb[(size_t)row * WW + gc + 2] : 0.f;
                    float p3 = (gc + 3 >= 0 && gc + 3 < WW) ? inb[(size_t)row * WW + gc + 3] : 0.f;
                    w2.x = packbf2(p0, p1);
                    w2.y = packbf2(p2, p3);
                }
                *(uint2*)(smem + row * XSW + 2 * q) = w2;
            }
        }
    }
    __syncthreads();

    // phase 2: fused horizontal 33-tap sums of x AND x^2; bf16-packed (Sx,Sxx) word per col.
    // 80 rows x 12 segs of 8 cols = 960 threads; 5 b128 reads each.
    {
        const int row = t % HH;
        const int seg = t / HH;
        if (seg < 12) {
            const uint32_t* xr = smem + row * XSW + seg * 4;
            uint4 v0 = *(const uint4*)(xr);
            uint4 v1 = *(const uint4*)(xr + 4);
            uint4 v2 = *(const uint4*)(xr + 8);
            uint4 v3 = *(const uint4*)(xr + 12);
            uint4 v4 = *(const uint4*)(xr + 16);
            // initial window e0..e32: packed pair accumulate, 2-way ILP split
            float l16 = bflo(W20(16));
            f32x2 pA; pA.x = l16;       pA.y = 0.f;
            f32x2 qA; qA.x = l16 * l16; qA.y = 0.f;
            f32x2 pB; pB.x = 0.f; pB.y = 0.f;
            f32x2 qB; qB.x = 0.f; qB.y = 0.f;
            #pragma unroll
            for (int q = 0; q < 16; q += 2) {
                f32x2 uA = uw(W20(q));
                f32x2 uB = uw(W20(q + 1));
                pA += uA;      pB += uB;
                qA += uA * uA; qB += uB * uB;
            }
            f32x2 ps = pA + pB, qs = qA + qB;
            float ax  = ps.x + ps.y;
            float axx = qs.x + qs.y;
            uint32_t* hw = Hxp + (seg * 8) * HXS + row + 16;
            #pragma unroll
            for (int k = 0; k < 4; ++k) {
                uint32_t wS = W20(k), wE = W20(k + 16);
                float lS = bflo(wS), hE = bfhi(wE);
                float a1x  = ax - lS + hE;
                float a1xx = axx - lS * lS + hE * hE;
                hw[(2 * k) * HXS]     = packbf2(ax, axx);
                hw[(2 * k + 1) * HXS] = packbf2(a1x, a1xx);
                if (k != 3) {
                    float hS = bfhi(wS), lN = bflo(W20(k + 17));
                    ax  = a1x - hS + lN;
                    axx = a1xx - hS * hS + lN * lN;
                }
            }
        }
    }
    __syncthreads();

    // phase 3: vertical 33-tap sums of (Sx,Sxx) via pk_add, bands of 16 rows to amortize init.
    // 96 cols x 5 bands = 480 threads; 12 contiguous b128 reads (words r0..r0+47).
    {
        const int c    = t % TW;
        const int band = t / TW;
        const int gc   = c0 + c;
        if (band < 5 && gc < WW) {
            const int r0 = band * 16;
            const uint32_t* hp = Hxp + c * HXS + r0;   // raw rows r0 .. r0+47
            uint4 R0  = *(const uint4*)(hp);
            uint4 R1  = *(const uint4*)(hp + 4);
            uint4 R2  = *(const uint4*)(hp + 8);
            uint4 R3  = *(const uint4*)(hp + 12);
            uint4 R4  = *(const uint4*)(hp + 16);
            uint4 R5  = *(const uint4*)(hp + 20);
            uint4 R6  = *(const uint4*)(hp + 24);
            uint4 R7  = *(const uint4*)(hp + 28);
            uint4 R8  = *(const uint4*)(hp + 32);
            uint4 R9  = *(const uint4*)(hp + 36);
            uint4 R10 = *(const uint4*)(hp + 40);
            uint4 R11 = *(const uint4*)(hp + 44);
            // init acc = sum of words 0..32 (3 ops/word via pk_add), 2-way split
            f32x2 aA = uw(W48(32));
            f32x2 aB; aB.x = 0.f; aB.y = 0.f;
            #pragma unroll
            for (int q = 0; q < 32; q += 2) {
                aA += uw(W48(q));
                aB += uw(W48(q + 1));
            }
            f32x2 acc = aA + aB;                       // {Sx_v, Sxx_v}
            const float icw = 1.0f / (float)(min(gc + RAD, WW - 1) - max(gc - RAD, 0) + 1);
            const int  xwoff  = (c + 16) >> 1;
            const bool hiHf   = ((c + 16) & 1) != 0;
            float* outb = out + (size_t)b * (HH * WW);
            #pragma unroll
            for (int k = 0; k < 16; ++k) {
                const int r = r0 + k;
                const float ninv = inv_ch[r] * icw;
                f32x2 me = acc * ninv;                 // {mean, E[x^2]} via v_pk_mul
                float var = fmaxf(me.y - me.x * me.x, 1e-24f);
#if defined(__has_builtin) && __has_builtin(__builtin_amdgcn_rsqf)
                float isd = __builtin_amdgcn_rsqf(var);
#else
                float isd = __builtin_amdgcn_rcpf(__builtin_amdgcn_sqrtf(var) + EPSF);
#endif
                uint32_t xw = smem[r * XSW + xwoff];
                float xv = hiHf ? bfhi(xw) : bflo(xw);
                outb[(size_t)r * WW + gc] = (xv - me.x) * isd;
                if (k != 15) {
                    acc += uw(W48(k + 33)) - uw(W48(k));   // 2x v_pk_add_f32
                }
            }
        }
    }
}

extern "C" void kernel_launch(void* const* d_in, const int* in_sizes, int n_in,
                              void* d_out, int out_size, void* d_ws, size_t ws_size,
                              hipStream_t stream) {
    const float* in = (const float*)d_in[0];
    float* out = (float*)d_out;

    const size_t lds_bytes = (size_t)TOT_WORDS * sizeof(uint32_t);  // 66624
    static bool attr_set = false;
    if (!attr_set) {
        (void)hipFuncSetAttribute((const void*)localnorm_kernel,
                                  hipFuncAttributeMaxDynamicSharedMemorySize,
                                  (int)lds_bytes);
        attr_set = true;
    }

    dim3 grid(BB * NSTRIP);
    dim3 block(NT);
    localnorm_kernel<<<grid, block, lds_bytes, stream>>>(in, out);
}

// Round 13
// 36.396 us; speedup vs baseline: 2.6383x; 1.0561x over previous
//
#include <hip/hip_runtime.h>
#include <hip/hip_bf16.h>
#include <math.h>

#define BB 64
#define HH 80
#define WW 3000
#define RAD 16
#define TW 96             // output columns per strip
#define XSW 68            // Xs words/row: 64 data + 4 pad (68 % 32 == 4 -> b128 bank-spread)
#define HXS 116           // Hxp col stride: 112 raw rows + 4 pad (116 % 32 == 20 -> b128 bank-spread)
#define NSTRIP 32         // ceil(3000/96)
#define NT 1024
#define EPSF 1e-8f

#define XS_WORDS (HH * XSW)             // 5440
#define HXP_OFF  XS_WORDS
#define HXP_WORDS (TW * HXS)            // 11136
#define ICH_OFF  (XS_WORDS + HXP_WORDS) // 16576 (byte 66304, 16B-aligned)
#define TOT_WORDS (ICH_OFF + HH)        // 16656 words = 66624 B -> 2 blocks/CU (32/32 wave slots)

typedef float f32x2 __attribute__((ext_vector_type(2)));
typedef float f32x4 __attribute__((ext_vector_type(4)));

__device__ __forceinline__ float bflo(uint32_t w) { return __uint_as_float(w << 16); }
__device__ __forceinline__ float bfhi(uint32_t w) { return __uint_as_float(w & 0xffff0000u); }
__device__ __forceinline__ uint32_t packbf2(float lo, float hi) {
    union { __hip_bfloat162 h2; uint32_t u; } u;
    u.h2 = __hip_bfloat162(__float2bfloat16(lo), __float2bfloat16(hi));
    return u.u;
}
// unpack a bf16-packed word into f32x2 {lo, hi}; pk_add accumulates both halves
__device__ __forceinline__ f32x2 uw(uint32_t w) {
    f32x2 r; r.x = bflo(w); r.y = bfhi(w); return r;
}

// compile-time-folding element selectors (named registers only — no arrays/unions)
#define E4(V, J) ((J) == 0 ? (V).x : ((J) == 1 ? (V).y : ((J) == 2 ? (V).z : (V).w)))
#define W24(Q) E4((Q) < 4 ? v0 : (Q) < 8 ? v1 : (Q) < 12 ? v2 : (Q) < 16 ? v3 : (Q) < 20 ? v4 : v5, (Q) & 3)
#define W48(Q) E4((Q) < 4 ? R0 : (Q) < 8 ? R1 : (Q) < 12 ? R2 : (Q) < 16 ? R3 : (Q) < 20 ? R4 : \
                  (Q) < 24 ? R5 : (Q) < 28 ? R6 : (Q) < 32 ? R7 : (Q) < 36 ? R8 : \
                  (Q) < 40 ? R9 : (Q) < 44 ? R10 : R11, (Q) & 3)
#define F16(K) E4((K) < 4 ? f0 : (K) < 8 ? f1 : (K) < 12 ? f2 : f3, (K) & 3)

__global__ __launch_bounds__(NT, 8)
void localnorm_kernel(const float* __restrict__ in, float* __restrict__ out) {
    extern __shared__ uint32_t smem[];
    uint32_t* Hxp = smem + HXP_OFF;          // Hxp[col][raw_r] at col*HXS + raw_r; raw_r = logical+16
    float* inv_ch = (float*)(smem + ICH_OFF);

    const int t     = threadIdx.x;
    const int strip = blockIdx.x % NSTRIP;
    const int b     = blockIdx.x / NSTRIP;
    const int c0    = strip * TW;

    // phase 0: per-row reciprocals + zero Hxp pad rows (raw 0..15 and 96..111) for all 96 cols
    if (t < HH) {
        int lo = max(t - RAD, 0), hi = min(t + RAD, HH - 1);
        inv_ch[t] = 1.0f / (float)(hi - lo + 1);
    }
    if (t < 768) {
        const int col = t >> 3;
        const int c8  = t & 7;
        const int off = col * HXS + ((c8 < 4) ? (c8 * 4) : (96 + (c8 - 4) * 4));
        *(uint4*)(Hxp + off) = make_uint4(0u, 0u, 0u, 0u);
    }

    // phase 1: load 128 cols x 80 rows, pack to bf16 pairs. 80 rows x 32 quads = 2560 tasks.
    {
        const float* inb = in + (size_t)b * (HH * WW);
        #pragma unroll
        for (int it = 0; it < 3; ++it) {
            const int id = t + it * NT;
            if (it < 2 || id < 2560) {
                const int row = id >> 5;
                const int q   = id & 31;
                const int gc  = c0 - 16 + 4 * q;
                uint2 w2;
                if (gc >= 0 && gc + 4 <= WW) {
                    float4 v = *(const float4*)(inb + (size_t)row * WW + gc);
                    w2.x = packbf2(v.x, v.y);
                    w2.y = packbf2(v.z, v.w);
                } else {
                    float p0 = (gc     >= 0 && gc     < WW) ? inb[(size_t)row * WW + gc]     : 0.f;
                    float p1 = (gc + 1 >= 0 && gc + 1 < WW) ? inb[(size_t)row * WW + gc + 1] : 0.f;
                    float p2 = (gc + 2 >= 0 && gc + 2 < WW) ? inb[(size_t)row * WW + gc + 2] : 0.f;
                    float p3 = (gc + 3 >= 0 && gc + 3 < WW) ? inb[(size_t)row * WW + gc + 3] : 0.f;
                    w2.x = packbf2(p0, p1);
                    w2.y = packbf2(p2, p3);
                }
                *(uint2*)(smem + row * XSW + 2 * q) = w2;
            }
        }
    }
    __syncthreads();

    // phase 2: fused horizontal 33-tap sums of x AND x^2, 16 output cols per thread.
    // 80 rows x 6 segs of 16 cols = 480 threads; 6 b128 reads each (24 words = 48 cols).
    {
        const int row = t % HH;
        const int s16 = t / HH;       // 0..5 active
        if (s16 < 6) {
            const uint32_t* xr = smem + row * XSW + s16 * 8;
            uint4 v0 = *(const uint4*)(xr);
            uint4 v1 = *(const uint4*)(xr + 4);
            uint4 v2 = *(const uint4*)(xr + 8);
            uint4 v3 = *(const uint4*)(xr + 12);
            uint4 v4 = *(const uint4*)(xr + 16);
            uint4 v5 = *(const uint4*)(xr + 20);
            // initial window e0..e32 (words 0..16): packed pair accumulate, 2-way ILP split
            float l16 = bflo(W24(16));
            f32x2 pA; pA.x = l16;       pA.y = 0.f;
            f32x2 qA; qA.x = l16 * l16; qA.y = 0.f;
            f32x2 pB; pB.x = 0.f; pB.y = 0.f;
            f32x2 qB; qB.x = 0.f; qB.y = 0.f;
            #pragma unroll
            for (int q = 0; q < 16; q += 2) {
                f32x2 uA = uw(W24(q));
                f32x2 uB = uw(W24(q + 1));
                pA += uA;      pB += uB;
                qA += uA * uA; qB += uB * uB;
            }
            f32x2 ps = pA + pB, qs = qA + qB;
            float ax  = ps.x + ps.y;
            float axx = qs.x + qs.y;
            uint32_t* hw = Hxp + (s16 * 16) * HXS + row + 16;
            #pragma unroll
            for (int k = 0; k < 8; ++k) {
                uint32_t wS = W24(k), wE = W24(k + 16);
                float lS = bflo(wS), hE = bfhi(wE);
                float a1x  = ax - lS + hE;
                float a1xx = axx - lS * lS + hE * hE;
                hw[(2 * k) * HXS]     = packbf2(ax, axx);
                hw[(2 * k + 1) * HXS] = packbf2(a1x, a1xx);
                if (k != 7) {
                    float hS = bfhi(wS), lN = bflo(W24(k + 17));
                    ax  = a1x - hS + lN;
                    axx = a1xx - hS * hS + lN * lN;
                }
            }
        }
    }
    __syncthreads();

    // phase 3: vertical 33-tap sums of (Sx,Sxx) via pk_add, bands of 16 rows.
    // 96 cols x 5 bands = 480 threads; 12 contiguous b128 reads (words r0..r0+47).
    {
        const int c    = t % TW;
        const int band = t / TW;
        const int gc   = c0 + c;
        if (band < 5 && gc < WW) {
            const int r0 = band * 16;
            const uint32_t* hp = Hxp + c * HXS + r0;   // raw rows r0 .. r0+47
            uint4 R0  = *(const uint4*)(hp);
            uint4 R1  = *(const uint4*)(hp + 4);
            uint4 R2  = *(const uint4*)(hp + 8);
            uint4 R3  = *(const uint4*)(hp + 12);
            uint4 R4  = *(const uint4*)(hp + 16);
            uint4 R5  = *(const uint4*)(hp + 20);
            uint4 R6  = *(const uint4*)(hp + 24);
            uint4 R7  = *(const uint4*)(hp + 28);
            uint4 R8  = *(const uint4*)(hp + 32);
            uint4 R9  = *(const uint4*)(hp + 36);
            uint4 R10 = *(const uint4*)(hp + 40);
            uint4 R11 = *(const uint4*)(hp + 44);
            // init acc = sum of words 0..32 (3 ops/word via pk_add), 2-way split
            f32x2 aA = uw(W48(32));
            f32x2 aB; aB.x = 0.f; aB.y = 0.f;
            #pragma unroll
            for (int q = 0; q < 32; q += 2) {
                aA += uw(W48(q));
                aB += uw(W48(q + 1));
            }
            f32x2 acc = aA + aB;                       // {Sx_v, Sxx_v}
            const float icw = 1.0f / (float)(min(gc + RAD, WW - 1) - max(gc - RAD, 0) + 1);
            f32x4 f0 = *(const f32x4*)(inv_ch + r0);
            f32x4 f1 = *(const f32x4*)(inv_ch + r0 + 4);
            f32x4 f2 = *(const f32x4*)(inv_ch + r0 + 8);
            f32x4 f3 = *(const f32x4*)(inv_ch + r0 + 12);
            const int  xwoff  = (c + 16) >> 1;
            const bool hiHf   = ((c + 16) & 1) != 0;
            float* outb = out + (size_t)b * (HH * WW);
            #pragma unroll
            for (int k = 0; k < 16; ++k) {
                const int r = r0 + k;
                const float ninv = F16(k) * icw;
                f32x2 me = acc * ninv;                 // {mean, E[x^2]} via v_pk_mul
                float var = fmaxf(me.y - me.x * me.x, 1e-24f);
#if defined(__has_builtin) && __has_builtin(__builtin_amdgcn_rsqf)
                float isd = __builtin_amdgcn_rsqf(var);
#else
                float isd = __builtin_amdgcn_rcpf(__builtin_amdgcn_sqrtf(var) + EPSF);
#endif
                uint32_t xw = smem[r * XSW + xwoff];
                float xv = hiHf ? bfhi(xw) : bflo(xw);
                outb[(size_t)r * WW + gc] = (xv - me.x) * isd;
                if (k != 15) {
                    acc += uw(W48(k + 33)) - uw(W48(k));   // 2x v_pk_add_f32
                }
            }
        }
    }
}

extern "C" void kernel_launch(void* const* d_in, const int* in_sizes, int n_in,
                              void* d_out, int out_size, void* d_ws, size_t ws_size,
                              hipStream_t stream) {
    const float* in = (const float*)d_in[0];
    float* out = (float*)d_out;

    const size_t lds_bytes = (size_t)TOT_WORDS * sizeof(uint32_t);  // 66624
    static bool attr_set = false;
    if (!attr_set) {
        (void)hipFuncSetAttribute((const void*)localnorm_kernel,
                                  hipFuncAttributeMaxDynamicSharedMemorySize,
                                  (int)lds_bytes);
        attr_set = true;
    }

    dim3 grid(BB * NSTRIP);
    dim3 block(NT);
    localnorm_kernel<<<grid, block, lds_bytes, stream>>>(in, out);
}

// Round 14
// 35.941 us; speedup vs baseline: 2.6717x; 1.0127x over previous
//
#include <hip/hip_runtime.h>
#include <hip/hip_bf16.h>
#include <math.h>

#define BB 64
#define HH 80
#define WW 3000
#define RAD 16
#define TW 80             // output columns per strip
#define NLOAD 112         // loaded columns = TW + 2*16 halo
#define XSW 112           // f32 Xs words/row: NO pad (global_load_lds needs linear dest)
#define HXS 116           // Hxp col stride: 112 raw rows + 4 pad (116 % 32 == 20 -> b128 bank-spread)
#define NSTRIP 38         // ceil(3000/80)
#define NT 1024
#define EPSF 1e-8f

#define XS_WORDS (HH * XSW)             // 8960
#define HXP_OFF  XS_WORDS
#define HXP_WORDS (TW * HXS)            // 9280
#define ICH_OFF  (XS_WORDS + HXP_WORDS) // 18240 (byte 72960, 16B-aligned)
#define TOT_WORDS (ICH_OFF + HH)        // 18320 words = 73280 B -> 2 blocks/CU (32/32 wave slots)

typedef float f32x2 __attribute__((ext_vector_type(2)));
typedef float f32x4 __attribute__((ext_vector_type(4)));

__device__ __forceinline__ float bflo(uint32_t w) { return __uint_as_float(w << 16); }
__device__ __forceinline__ float bfhi(uint32_t w) { return __uint_as_float(w & 0xffff0000u); }
__device__ __forceinline__ uint32_t packbf2(float lo, float hi) {
    union { __hip_bfloat162 h2; uint32_t u; } u;
    u.h2 = __hip_bfloat162(__float2bfloat16(lo), __float2bfloat16(hi));
    return u.u;
}
// unpack a bf16-packed word into f32x2 {lo, hi}; pk_add accumulates both halves
__device__ __forceinline__ f32x2 uw(uint32_t w) {
    f32x2 r; r.x = bflo(w); r.y = bfhi(w); return r;
}

#if defined(__has_builtin)
#if __has_builtin(__builtin_amdgcn_global_load_lds)
#define HAVE_GLL 1
__device__ __forceinline__ void gload_lds16(const float* g, float* l) {
    __builtin_amdgcn_global_load_lds(
        (const __attribute__((address_space(1))) void*)g,
        (__attribute__((address_space(3))) void*)l, 16, 0, 0);
}
#endif
#endif

// compile-time-folding element selectors (named registers only — no arrays/unions)
#define E4(V, J) ((J) == 0 ? (V).x : ((J) == 1 ? (V).y : ((J) == 2 ? (V).z : (V).w)))
#define F48(Q) E4((Q) < 4 ? G0 : (Q) < 8 ? G1 : (Q) < 12 ? G2 : (Q) < 16 ? G3 : (Q) < 20 ? G4 : \
                  (Q) < 24 ? G5 : (Q) < 28 ? G6 : (Q) < 32 ? G7 : (Q) < 36 ? G8 : \
                  (Q) < 40 ? G9 : (Q) < 44 ? G10 : G11, (Q) & 3)
#define W48(Q) E4((Q) < 4 ? R0 : (Q) < 8 ? R1 : (Q) < 12 ? R2 : (Q) < 16 ? R3 : (Q) < 20 ? R4 : \
                  (Q) < 24 ? R5 : (Q) < 28 ? R6 : (Q) < 32 ? R7 : (Q) < 36 ? R8 : \
                  (Q) < 40 ? R9 : (Q) < 44 ? R10 : R11, (Q) & 3)
#define F16(K) E4((K) < 4 ? f0 : (K) < 8 ? f1 : (K) < 12 ? f2 : f3, (K) & 3)

__global__ __launch_bounds__(NT, 8)
void localnorm_kernel(const float* __restrict__ in, float* __restrict__ out) {
    extern __shared__ uint32_t smem[];
    float*    smemf = (float*)smem;
    uint32_t* Hxp   = smem + HXP_OFF;        // Hxp[col][raw_r] at col*HXS + raw_r; raw_r = logical+16
    float*   inv_ch = (float*)(smem + ICH_OFF);

    const int t     = threadIdx.x;
    const int strip = blockIdx.x % NSTRIP;
    const int b     = blockIdx.x / NSTRIP;
    const int c0    = strip * TW;
    const float* inb = in + (size_t)b * (HH * WW);

    // phase 0: per-row reciprocals + zero Hxp pad rows (raw 0..15 and 96..111) for 80 cols
    if (t < HH) {
        int lo = max(t - RAD, 0), hi = min(t + RAD, HH - 1);
        inv_ch[t] = 1.0f / (float)(hi - lo + 1);
    }
    if (t < 640) {
        const int col = t >> 3;
        const int c8  = t & 7;
        const int off = col * HXS + ((c8 < 4) ? (c8 * 4) : (96 + (c8 - 4) * 4));
        *(uint4*)(Hxp + off) = make_uint4(0u, 0u, 0u, 0u);
    }

    // phase 1: stage 112 cols x 80 rows of f32 into Xs.
    // Interior strips: pure DMA via global_load_lds (2240 16B chunks, linear LDS dest).
    // Edge strips (0, 37): scalar bounds-checked fallback.
    bool dma = false;
#ifdef HAVE_GLL
    dma = (c0 >= 16) && (c0 + NLOAD - 16 <= WW);
#endif
    if (dma) {
#ifdef HAVE_GLL
        const float* gsrc = inb + (c0 - 16);
        #pragma unroll
        for (int i = 0; i < 3; ++i) {
            const int ck = t + i * NT;                 // chunk id: 4 words at Xs word 4*ck
            if (i < 2 || ck < 2240) {
                const int row = ck / 28;               // 28 chunks per 112-word row
                const int m   = ck - row * 28;
                gload_lds16(gsrc + (size_t)row * WW + 4 * m, smemf + 4 * ck);
            }
        }
#endif
    } else {
        #pragma unroll
        for (int it = 0; it < 3; ++it) {
            const int id = t + it * NT;
            if (it < 2 || id < 2240) {
                const int row = id / 28;
                const int q   = id - row * 28;
                const int gc  = c0 - 16 + 4 * q;
                const float* rp = inb + (size_t)row * WW;
                f32x4 v;
                if (gc >= 0 && gc + 4 <= WW) {
                    v = *(const f32x4*)(rp + gc);
                } else {
                    v.x = (gc     >= 0 && gc     < WW) ? rp[gc]     : 0.f;
                    v.y = (gc + 1 >= 0 && gc + 1 < WW) ? rp[gc + 1] : 0.f;
                    v.z = (gc + 2 >= 0 && gc + 2 < WW) ? rp[gc + 2] : 0.f;
                    v.w = (gc + 3 >= 0 && gc + 3 < WW) ? rp[gc + 3] : 0.f;
                }
                *(f32x4*)(smemf + row * XSW + 4 * q) = v;
            }
        }
    }
    __syncthreads();   // drains vmcnt -> DMA'd Xs visible

    // phase 2: fused horizontal 33-tap sums of x AND x^2 from f32 Xs (no unpack);
    // bf16-packed (Sx,Sxx) word per col into Hxp. 80 rows x 5 segs of 16 cols = 400 threads.
    {
        const int row = t % HH;
        const int seg = t / HH;       // 0..4 active
        if (seg < 5) {
            const float* xr = smemf + row * XSW + seg * 16;
            f32x4 G0  = *(const f32x4*)(xr);
            f32x4 G1  = *(const f32x4*)(xr + 4);
            f32x4 G2  = *(const f32x4*)(xr + 8);
            f32x4 G3  = *(const f32x4*)(xr + 12);
            f32x4 G4  = *(const f32x4*)(xr + 16);
            f32x4 G5  = *(const f32x4*)(xr + 20);
            f32x4 G6  = *(const f32x4*)(xr + 24);
            f32x4 G7  = *(const f32x4*)(xr + 28);
            f32x4 G8  = *(const f32x4*)(xr + 32);
            f32x4 G9  = *(const f32x4*)(xr + 36);
            f32x4 G10 = *(const f32x4*)(xr + 40);
            f32x4 G11 = *(const f32x4*)(xr + 44);
            // initial window F(0..32), 2-way ILP split
            float e32 = F48(32);
            float axA = e32, axB = 0.f;
            float qxA = e32 * e32, qxB = 0.f;
            #pragma unroll
            for (int q = 0; q < 32; q += 2) {
                float fa = F48(q), fb = F48(q + 1);
                axA += fa;                 axB += fb;
                qxA = fmaf(fa, fa, qxA);   qxB = fmaf(fb, fb, qxB);
            }
            float ax = axA + axB, axx = qxA + qxB;
            uint32_t* hw = Hxp + (seg * 16) * HXS + row + 16;
            #pragma unroll
            for (int k = 0; k < 8; ++k) {
                float fs = F48(2 * k), fe = F48(2 * k + 33);
                float a1x  = ax - fs + fe;
                float a1xx = fmaf(fe, fe, fmaf(-fs, fs, axx));
                hw[(2 * k) * HXS]     = packbf2(ax, axx);
                hw[(2 * k + 1) * HXS] = packbf2(a1x, a1xx);
                if (k != 7) {
                    float fs2 = F48(2 * k + 1), fe2 = F48(2 * k + 34);
                    ax  = a1x - fs2 + fe2;
                    axx = fmaf(fe2, fe2, fmaf(-fs2, fs2, a1xx));
                }
            }
        }
    }
    __syncthreads();

    // phase 3: vertical 33-tap sums of (Sx,Sxx) via pk_add, bands of 16 rows.
    // 80 cols x 5 bands = 400 threads; 12 contiguous b128 reads (words r0..r0+47).
    {
        const int c    = t % TW;
        const int band = t / TW;
        const int gc   = c0 + c;
        if (band < 5 && gc < WW) {
            const int r0 = band * 16;
            const uint32_t* hp = Hxp + c * HXS + r0;   // raw rows r0 .. r0+47
            uint4 R0  = *(const uint4*)(hp);
            uint4 R1  = *(const uint4*)(hp + 4);
            uint4 R2  = *(const uint4*)(hp + 8);
            uint4 R3  = *(const uint4*)(hp + 12);
            uint4 R4  = *(const uint4*)(hp + 16);
            uint4 R5  = *(const uint4*)(hp + 20);
            uint4 R6  = *(const uint4*)(hp + 24);
            uint4 R7  = *(const uint4*)(hp + 28);
            uint4 R8  = *(const uint4*)(hp + 32);
            uint4 R9  = *(const uint4*)(hp + 36);
            uint4 R10 = *(const uint4*)(hp + 40);
            uint4 R11 = *(const uint4*)(hp + 44);
            // init acc = sum of words 0..32 (3 ops/word via pk_add), 2-way split
            f32x2 aA = uw(W48(32));
            f32x2 aB; aB.x = 0.f; aB.y = 0.f;
            #pragma unroll
            for (int q = 0; q < 32; q += 2) {
                aA += uw(W48(q));
                aB += uw(W48(q + 1));
            }
            f32x2 acc = aA + aB;                       // {Sx_v, Sxx_v}
            const float icw = 1.0f / (float)(min(gc + RAD, WW - 1) - max(gc - RAD, 0) + 1);
            f32x4 f0 = *(const f32x4*)(inv_ch + r0);
            f32x4 f1 = *(const f32x4*)(inv_ch + r0 + 4);
            f32x4 f2 = *(const f32x4*)(inv_ch + r0 + 8);
            f32x4 f3 = *(const f32x4*)(inv_ch + r0 + 12);
            float* outb = out + (size_t)b * (HH * WW);
            #pragma unroll
            for (int k = 0; k < 16; ++k) {
                const int r = r0 + k;
                const float ninv = F16(k) * icw;
                f32x2 me = acc * ninv;                 // {mean, E[x^2]} via v_pk_mul
                float var = fmaxf(me.y - me.x * me.x, 1e-24f);
#if defined(__has_builtin) && __has_builtin(__builtin_amdgcn_rsqf)
                float isd = __builtin_amdgcn_rsqf(var);
#else
                float isd = __builtin_amdgcn_rcpf(__builtin_amdgcn_sqrtf(var) + EPSF);
#endif
                float xv = smemf[r * XSW + c + 16];    // f32 x, no unpack
                outb[(size_t)r * WW + gc] = (xv - me.x) * isd;
                if (k != 15) {
                    acc += uw(W48(k + 33)) - uw(W48(k));   // 2x v_pk_add_f32
                }
            }
        }
    }
}

extern "C" void kernel_launch(void* const* d_in, const int* in_sizes, int n_in,
                              void* d_out, int out_size, void* d_ws, size_t ws_size,
                              hipStream_t stream) {
    const float* in = (const float*)d_in[0];
    float* out = (float*)d_out;

    const size_t lds_bytes = (size_t)TOT_WORDS * sizeof(uint32_t);  // 73280
    static bool attr_set = false;
    if (!attr_set) {
        (void)hipFuncSetAttribute((const void*)localnorm_kernel,
                                  hipFuncAttributeMaxDynamicSharedMemorySize,
                                  (int)lds_bytes);
        attr_set = true;
    }

    dim3 grid(BB * NSTRIP);
    dim3 block(NT);
    localnorm_kernel<<<grid, block, lds_bytes, stream>>>(in, out);
}